// Round 6
// baseline (111.228 us; speedup 1.0000x reference)
//
#include <hip/hip_runtime.h>

// ---------- types ----------
typedef __bf16 bf16;
typedef __bf16 bf16x4 __attribute__((ext_vector_type(4)));
typedef __bf16 bf16x8 __attribute__((ext_vector_type(8)));
typedef float f32x4 __attribute__((ext_vector_type(4)));

#define ALPHA_ 0.125f   // 1/sqrt(64)

// H=8 heads, B=16, N=512, HID=512, D=64, M = B*N = 8192
// ws layout (bytes):
//   xb    [8192][512] bf16             @ 0          (8,388,608)
//   wcat  [1536][512] bf16 (B^T)       @ 8388608    (1,572,864)
//   wot   [512][512]  bf16 (Wo^T)      @ 9961472    (524,288)
//   Q     [8][8192][64] bf16           @ 10485760   (8,388,608)
//   K     [8][8192][64] bf16           @ 18874368   (8,388,608)
//   Vt    [8][16][64][512] bf16        @ 27262976   (8,388,608)
//   Oatt  [8192][512] bf16             @ 35651584   (8,388,608)

__device__ __forceinline__ void gload16(const void* g, void* l) {
  __builtin_amdgcn_global_load_lds((__attribute__((address_space(1))) void*)(g),
                                   (__attribute__((address_space(3))) void*)(l),
                                   16, 0, 0);
}

// ---------- prep kernels ----------
__global__ void cast_x_kernel(const float* __restrict__ x, bf16* __restrict__ xb) {
  int i = blockIdx.x * 256 + threadIdx.x;
  float4 v = ((const float4*)x)[i];
  bf16x4 o = {(bf16)v.x, (bf16)v.y, (bf16)v.z, (bf16)v.w};
  ((bf16x4*)xb)[i] = o;
}

__global__ void prep_w_kernel(const float* __restrict__ Wq, const float* __restrict__ Wk,
                              const float* __restrict__ Wv, bf16* __restrict__ wcat) {
  int i = blockIdx.x * 256 + threadIdx.x;          // 786,432 = 1536*512
  int h = i & 511, j = i >> 9;
  int qkv = j >> 9, g = (j >> 6) & 7, d = j & 63;
  const float* W = (qkv == 0) ? Wq : ((qkv == 1) ? Wk : Wv);
  wcat[i] = (bf16)W[((g << 9) + h) * 64 + d];      // wcat[j][h] = W[g][h][d]
}

__global__ void prep_wo_kernel(const float* __restrict__ Wo, bf16* __restrict__ wot) {
  int i = blockIdx.x * 256 + threadIdx.x;          // 262,144
  int k = i & 511, n = i >> 9;
  wot[i] = (bf16)Wo[(k << 9) + n];                 // wot[n][k] = Wo[k][n]
}

// ---------- GEMM: C = A[M,K] * Bt[N,K]^T, bf16 in, f32 acc ----------
template <int MODE>
__global__ __launch_bounds__(256, 2) void gemm_bt_kernel(
    const bf16* __restrict__ A, const bf16* __restrict__ Bt, int Kdim, int Ndim,
    float* __restrict__ Cf, bf16* __restrict__ Qo, bf16* __restrict__ Ko,
    bf16* __restrict__ Vto) {
  __shared__ bf16 lA[128 * 32];
  __shared__ bf16 lB[128 * 32];
  const int t = threadIdx.x;
  const int w = t >> 6;
  const int lane = t & 63;
  const int lhi = lane >> 4, llo = lane & 15;
  const int m0 = blockIdx.y * 128, n0 = blockIdx.x * 128;
  const int wr = (w >> 1) * 64, wc = (w & 1) * 64;

  f32x4 acc[4][4] = {};
  const int nkt = Kdim >> 5;
  for (int kt = 0; kt < nkt; ++kt) {
#pragma unroll
    for (int c = 0; c < 2; ++c) {
      int u = c * 256 + t;
      const bf16* ga = A + (size_t)(m0 + (u >> 2)) * Kdim + kt * 32 + (u & 3) * 8;
      gload16(ga, &lA[c * 2048 + w * 512]);
      const bf16* gb = Bt + (size_t)(n0 + (u >> 2)) * Kdim + kt * 32 + (u & 3) * 8;
      gload16(gb, &lB[c * 2048 + w * 512]);
    }
    __syncthreads();
    bf16x8 af[4], bfr[4];
#pragma unroll
    for (int i = 0; i < 4; ++i) {
      af[i] = *(const bf16x8*)&lA[(wr + i * 16 + llo) * 32 + lhi * 8];
      bfr[i] = *(const bf16x8*)&lB[(wc + i * 16 + llo) * 32 + lhi * 8];
    }
#pragma unroll
    for (int i = 0; i < 4; ++i)
#pragma unroll
      for (int j = 0; j < 4; ++j)
        acc[i][j] = __builtin_amdgcn_mfma_f32_16x16x32_bf16(af[i], bfr[j], acc[i][j], 0, 0, 0);
    __syncthreads();
  }

#pragma unroll
  for (int i = 0; i < 4; ++i) {
    int row = m0 + wr + i * 16 + lhi * 4;
#pragma unroll
    for (int j = 0; j < 4; ++j) {
      int col = n0 + wc + j * 16 + llo;
#pragma unroll
      for (int r = 0; r < 4; ++r) {
        float v = acc[i][j][r];
        int rr = row + r;
        if (MODE == 0) {
          int qkv = col >> 9, g = (col >> 6) & 7, d = col & 63;
          bf16 bv = (bf16)v;
          if (qkv == 0)
            Qo[((size_t)g * 8192 + rr) * 64 + d] = bv;
          else if (qkv == 1)
            Ko[((size_t)g * 8192 + rr) * 64 + d] = bv;
          else {
            int b = rr >> 9, n = rr & 511;
            Vto[(((size_t)g * 16 + b) * 64 + d) * 512 + n] = bv;
          }
        } else {
          Cf[(size_t)rr * Ndim + col] = v;
        }
      }
    }
  }
}

// ---------- fused attention ----------
// grid (8 qtiles, 16 batch, 8 heads), 256 threads (4 waves x 16 q-rows)
// KVBLK=64. REG-STAGED K/V (T14): global->VGPR loads give the compiler
// PRECISE register-level vmcnt deps (emits vmcnt(4), never a drain; no
// LDS-DMA alias hazard), then swizzled ds_write_b128 into a double-buffered
// LDS tile. ONE barrier per iteration (double-buffer WAR analysis: reads of
// buf[cur] in iter t-2 complete before barrier t-1, so writes at iter t are
// safe). Edge bias: single reg buffer, refilled right after softmax consumes
// it. S^T trick: mfma(K,Q) -> lane owns q=llo; P assembled in-register via
// cvt_pk + permlane swaps (T12). Peak VGPR ~110 < 128 (no spills).
__global__ __launch_bounds__(256, 4) void attn_kernel(
    const bf16* __restrict__ Qa, const bf16* __restrict__ Ka,
    const bf16* __restrict__ Vta, const float* __restrict__ edge,
    bf16* __restrict__ Oatt) {
  __shared__ bf16 lK[2][64 * 64];
  __shared__ bf16 lV[2][64 * 64];
  const int t = threadIdx.x, lane = t & 63;
  const int lhi = lane >> 4, llo = lane & 15;
  const int qt = blockIdx.x, b = blockIdx.y, g = blockIdx.z;
  const int q0 = qt * 64 + (t >> 6) * 16;
  const bf16* Qg = Qa + ((size_t)g * 8192 + b * 512) * 64;
  const bf16* Kg = Ka + ((size_t)g * 8192 + b * 512) * 64;
  const bf16* Vg = Vta + ((size_t)g * 16 + b) * (64 * 512);
  const float* eg = edge + ((size_t)g * 16 + b) * (512 * 512);

  // Q fragments (B-operand layout: lane col = llo = q-row)
  bf16x8 qf[2];
#pragma unroll
  for (int ks = 0; ks < 2; ++ks)
    qf[ks] = *(const bf16x8*)(Qg + (size_t)(q0 + llo) * 64 + ks * 32 + lhi * 8);

  f32x4 oacc[4] = {};
  float mrow = -3e38f, lrow = 0.f;

  // staging coords: thread t stages rows r0 = t>>3 and r1 = r0+32,
  // column chunk c8 = (t&7)*8 (16 B). Swizzle applied on the ds_write addr.
  const int r0 = t >> 3;
  const int r1 = r0 + 32;                 // (r1 & 7) == (r0 & 7)
  const int c8 = (t & 7) * 8;
  const int lw0 = (r0 * 64 + c8) ^ ((r0 & 7) << 3);   // LDS write offsets
  const int lw1 = (r1 * 64 + c8) ^ ((r0 & 7) << 3);

  // ---- prologue: stage tile 0 into regs, edge tile 0 into regs ----
  bf16x8 k0s = *(const bf16x8*)(Kg + (size_t)r0 * 64 + c8);
  bf16x8 k1s = *(const bf16x8*)(Kg + (size_t)r1 * 64 + c8);
  bf16x8 v0s = *(const bf16x8*)(Vg + (size_t)r0 * 512 + c8);
  bf16x8 v1s = *(const bf16x8*)(Vg + (size_t)r1 * 512 + c8);
  f32x4 ef[4];
#pragma unroll
  for (int ni = 0; ni < 4; ++ni)
    ef[ni] = *(const f32x4*)(eg + (size_t)(q0 + llo) * 512 + ni * 16 + lhi * 4);

#pragma unroll
  for (int it = 0; it < 8; ++it) {
    const int cur = it & 1;
    // ---- A: write staged tile t into LDS buf[cur] (compiler waits vmcnt
    //         precisely on k0s..v1s register deps -> vmcnt(4)) ----
    *(bf16x8*)&lK[cur][lw0] = k0s;
    *(bf16x8*)&lK[cur][lw1] = k1s;
    *(bf16x8*)&lV[cur][lw0] = v0s;
    *(bf16x8*)&lV[cur][lw1] = v1s;
    // ---- B: issue tile t+1 staged loads (in flight across the barrier
    //         and the whole compute phase) ----
    if (it < 7) {
      const int kvn = (it + 1) * 64;
      k0s = *(const bf16x8*)(Kg + (size_t)(kvn + r0) * 64 + c8);
      k1s = *(const bf16x8*)(Kg + (size_t)(kvn + r1) * 64 + c8);
      v0s = *(const bf16x8*)(Vg + (size_t)r0 * 512 + kvn + c8);
      v1s = *(const bf16x8*)(Vg + (size_t)r1 * 512 + kvn + c8);
    }
    // ---- C: one barrier per iteration (lgkm drain only; vmem stays hot) --
    asm volatile("s_waitcnt lgkmcnt(0)" ::: "memory");
    __builtin_amdgcn_sched_barrier(0);
    __builtin_amdgcn_s_barrier();
    __builtin_amdgcn_sched_barrier(0);

    // ---- D: S^T = K Q^T : sc[ni][r] = S[q=llo][kv = ni*16 + lhi*4 + r] ----
    f32x4 sc[4] = {};
    __builtin_amdgcn_s_setprio(1);
#pragma unroll
    for (int ks = 0; ks < 2; ++ks) {
      bf16x8 kf[4];
#pragma unroll
      for (int ni = 0; ni < 4; ++ni) {
        int row = ni * 16 + llo;
        kf[ni] = *(const bf16x8*)&lK[cur][(row * 64 + ks * 32 + lhi * 8) ^ ((row & 7) << 3)];
      }
#pragma unroll
      for (int ni = 0; ni < 4; ++ni)
        sc[ni] = __builtin_amdgcn_mfma_f32_16x16x32_bf16(kf[ni], qf[ks], sc[ni], 0, 0, 0);
    }
    __builtin_amdgcn_s_setprio(0);

    // ---- E: edge add + online softmax (consumes ef; compiler emits
    //         vmcnt(4) keeping tile t+1 staged loads in flight) ----
    float mx = -3e38f;
#pragma unroll
    for (int ni = 0; ni < 4; ++ni)
#pragma unroll
      for (int r = 0; r < 4; ++r) {
        float sv = fmaf(ALPHA_, sc[ni][r], ef[ni][r]);
        sc[ni][r] = sv;
        mx = fmaxf(mx, sv);
      }
    mx = fmaxf(mx, __shfl_xor(mx, 16));
    mx = fmaxf(mx, __shfl_xor(mx, 32));
    float mnew = fmaxf(mrow, mx);
    float s = __expf(mrow - mnew);
    mrow = mnew;
    float rsum = 0.f;
#pragma unroll
    for (int ni = 0; ni < 4; ++ni)
#pragma unroll
      for (int r = 0; r < 4; ++r) {
        float p = __expf(sc[ni][r] - mnew);
        sc[ni][r] = p;
        rsum += p;
      }
    rsum += __shfl_xor(rsum, 16);
    rsum += __shfl_xor(rsum, 32);
    lrow = lrow * s + rsum;

    // ---- F: refill edge regs for tile t+1 (consumed next iteration) ----
    if (it < 7) {
      const int kvn = (it + 1) * 64;
#pragma unroll
      for (int ni = 0; ni < 4; ++ni)
        ef[ni] = *(const f32x4*)(eg + (size_t)(q0 + llo) * 512 + kvn + ni * 16 + lhi * 4);
    }

    // rescale O accumulator (row r needs scale of q-row lhi*4+r, held at llo=lhi*4+r)
#pragma unroll
    for (int r = 0; r < 4; ++r) {
      float sq = __shfl(s, (lane & 48) | (lhi * 4 + r));
#pragma unroll
      for (int nc = 0; nc < 4; ++nc) oacc[nc][r] *= sq;
    }

    // ---- G: P A-frag via cvt_pk + permlane swaps; O += P V ----
    __builtin_amdgcn_s_setprio(1);
#pragma unroll
    for (int ks2 = 0; ks2 < 2; ++ks2) {
      const int n0 = ks2 * 2, n1 = n0 + 1;
      unsigned xa, xb, ya, yb;
      asm("v_cvt_pk_bf16_f32 %0, %1, %2" : "=v"(xa) : "v"(sc[n0][0]), "v"(sc[n0][1]));
      asm("v_cvt_pk_bf16_f32 %0, %1, %2" : "=v"(xb) : "v"(sc[n0][2]), "v"(sc[n0][3]));
      asm("v_cvt_pk_bf16_f32 %0, %1, %2" : "=v"(ya) : "v"(sc[n1][0]), "v"(sc[n1][1]));
      asm("v_cvt_pk_bf16_f32 %0, %1, %2" : "=v"(yb) : "v"(sc[n1][2]), "v"(sc[n1][3]));
      asm("v_permlane32_swap_b32 %0, %1" : "+v"(xa), "+v"(ya));
      asm("v_permlane16_swap_b32 %0, %1" : "+v"(xa), "+v"(ya));
      asm("v_permlane32_swap_b32 %0, %1" : "+v"(xb), "+v"(yb));
      asm("v_permlane16_swap_b32 %0, %1" : "+v"(xb), "+v"(yb));
      union { unsigned wd[4]; bf16x8 v; } fu;
      fu.wd[0] = xa; fu.wd[1] = xb; fu.wd[2] = ya; fu.wd[3] = yb;
      bf16x8 pf = fu.v;

      bf16x8 vf[4];
#pragma unroll
      for (int nc = 0; nc < 4; ++nc) {
        int row = nc * 16 + llo;
        vf[nc] = *(const bf16x8*)&lV[cur][(row * 64 + ks2 * 32 + lhi * 8) ^ ((row & 7) << 3)];
      }
#pragma unroll
      for (int nc = 0; nc < 4; ++nc)
        oacc[nc] = __builtin_amdgcn_mfma_f32_16x16x32_bf16(pf, vf[nc], oacc[nc], 0, 0, 0);
    }
    __builtin_amdgcn_s_setprio(0);
    // no trailing barrier: next iteration's ds_writes target buf[cur^1],
    // whose readers all passed THIS iteration's barrier already.
  }

  // ---- normalize + write Oatt [b*512+q][g*64+d] ----
  float rcpl = 1.0f / lrow;
#pragma unroll
  for (int r = 0; r < 4; ++r) {
    float lr = __shfl(rcpl, (lane & 48) | (lhi * 4 + r));
    int qrow = q0 + lhi * 4 + r;
#pragma unroll
    for (int nc = 0; nc < 4; ++nc) {
      float ov = oacc[nc][r] * lr;
      Oatt[((size_t)b * 512 + qrow) * 512 + g * 64 + nc * 16 + llo] = (bf16)ov;
    }
  }
}

// ---------- launch ----------
extern "C" void kernel_launch(void* const* d_in, const int* in_sizes, int n_in,
                              void* d_out, int out_size, void* d_ws, size_t ws_size,
                              hipStream_t stream) {
  (void)in_sizes; (void)n_in; (void)out_size; (void)ws_size;
  const float* x = (const float*)d_in[0];
  const float* edge = (const float*)d_in[1];
  const float* Wq = (const float*)d_in[2];
  const float* Wk = (const float*)d_in[3];
  const float* Wv = (const float*)d_in[4];
  const float* Wo = (const float*)d_in[5];
  float* out = (float*)d_out;

  char* ws = (char*)d_ws;
  bf16* xb   = (bf16*)(ws + 0);
  bf16* wcat = (bf16*)(ws + 8388608);
  bf16* wot  = (bf16*)(ws + 9961472);
  bf16* Qa   = (bf16*)(ws + 10485760);
  bf16* Ka   = (bf16*)(ws + 18874368);
  bf16* Vta  = (bf16*)(ws + 27262976);
  bf16* Oatt = (bf16*)(ws + 35651584);

  cast_x_kernel<<<4096, 256, 0, stream>>>(x, xb);
  prep_w_kernel<<<3072, 256, 0, stream>>>(Wq, Wk, Wv, wcat);
  prep_wo_kernel<<<1024, 256, 0, stream>>>(Wo, wot);

  // QKV: A=xb [8192,512], Bt=wcat [1536,512]
  gemm_bt_kernel<0><<<dim3(12, 64), 256, 0, stream>>>(xb, wcat, 512, 1536,
                                                      nullptr, Qa, Ka, Vta);
  // fused attention
  attn_kernel<<<dim3(8, 16, 8), 256, 0, stream>>>(Qa, Ka, Vta, edge, Oatt);
  // output projection: A=Oatt [8192,512], Bt=wot [512,512] -> f32 out
  gemm_bt_kernel<1><<<dim3(4, 64), 256, 0, stream>>>(Oatt, wot, 512, 512,
                                                     out, nullptr, nullptr, nullptr);
}

// Round 8
// 108.745 us; speedup vs baseline: 1.0228x; 1.0228x over previous
//
#include <hip/hip_runtime.h>

// ---------- types ----------
typedef __bf16 bf16;
typedef __bf16 bf16x4 __attribute__((ext_vector_type(4)));
typedef __bf16 bf16x8 __attribute__((ext_vector_type(8)));
typedef float f32x4 __attribute__((ext_vector_type(4)));

#define ALPHA_ 0.125f   // 1/sqrt(64)

// H=8 heads, B=16, N=512, HID=512, D=64, M = B*N = 8192
// ws layout (bytes):
//   xb    [8192][512] bf16             @ 0          (8,388,608)
//   wcat  [1536][512] bf16 (B^T)       @ 8388608    (1,572,864)
//   wot   [512][512]  bf16 (Wo^T)      @ 9961472    (524,288)
//   Q     [8][8192][64] bf16           @ 10485760   (8,388,608)
//   K     [8][8192][64] bf16           @ 18874368   (8,388,608)
//   Vt    [8][16][64][512] bf16        @ 27262976   (8,388,608)
//   Oatt  [8192][512] bf16             @ 35651584   (8,388,608)

__device__ __forceinline__ void gload16(const void* g, void* l) {
  __builtin_amdgcn_global_load_lds((__attribute__((address_space(1))) void*)(g),
                                   (__attribute__((address_space(3))) void*)(l),
                                   16, 0, 0);
}

// ---------- prep kernels ----------
__global__ void cast_x_kernel(const float* __restrict__ x, bf16* __restrict__ xb) {
  int i = blockIdx.x * 256 + threadIdx.x;
  float4 v = ((const float4*)x)[i];
  bf16x4 o = {(bf16)v.x, (bf16)v.y, (bf16)v.z, (bf16)v.w};
  ((bf16x4*)xb)[i] = o;
}

__global__ void prep_w_kernel(const float* __restrict__ Wq, const float* __restrict__ Wk,
                              const float* __restrict__ Wv, bf16* __restrict__ wcat) {
  int i = blockIdx.x * 256 + threadIdx.x;          // 786,432 = 1536*512
  int h = i & 511, j = i >> 9;
  int qkv = j >> 9, g = (j >> 6) & 7, d = j & 63;
  const float* W = (qkv == 0) ? Wq : ((qkv == 1) ? Wk : Wv);
  wcat[i] = (bf16)W[((g << 9) + h) * 64 + d];      // wcat[j][h] = W[g][h][d]
}

__global__ void prep_wo_kernel(const float* __restrict__ Wo, bf16* __restrict__ wot) {
  int i = blockIdx.x * 256 + threadIdx.x;          // 262,144
  int k = i & 511, n = i >> 9;
  wot[i] = (bf16)Wo[(k << 9) + n];                 // wot[n][k] = Wo[k][n]
}

// ---------- GEMM: C = A[M,K] * Bt[N,K]^T, bf16 in, f32 acc ----------
// 2-phase double-buffered schedule (T3-min): stage(t+1) issued BEFORE
// compute(t); ONE vmcnt(0)+barrier per K-step (prefetch hides under MFMA).
// Tile BM x BN (BM=64*RM, BN=64*RN), BK=32, 4 waves in 2x2 -> wave tile
// (BM/2)x(BN/2). MODE 0: QKV scatter epilogue; MODE 1: f32 C write.
template <int RM, int RN, int MODE>
__global__ __launch_bounds__(256, 2) void gemm2_kernel(
    const bf16* __restrict__ A, const bf16* __restrict__ Bt, int Kdim, int Ndim,
    float* __restrict__ Cf, bf16* __restrict__ Qo, bf16* __restrict__ Ko,
    bf16* __restrict__ Vto) {
  constexpr int BM = RM * 64, BN = RN * 64;
  constexpr int MI = BM / 32, NJ = BN / 32;   // fragments per wave
  __shared__ bf16 lA[2][BM * 32];
  __shared__ bf16 lB[2][BN * 32];
  const int t = threadIdx.x;
  const int w = t >> 6;
  const int lane = t & 63;
  const int lhi = lane >> 4, llo = lane & 15;
  const int m0 = blockIdx.y * BM, n0 = blockIdx.x * BN;
  const int wr = (w >> 1) * (BM / 2), wc = (w & 1) * (BN / 2);

  f32x4 acc[MI][NJ] = {};
  const int nkt = Kdim >> 5;

  auto stage = [&](int buf, int kt) {
#pragma unroll
    for (int c = 0; c < RM; ++c) {
      int u = c * 256 + t;
      gload16(A + (size_t)(m0 + (u >> 2)) * Kdim + kt * 32 + (u & 3) * 8,
              &lA[buf][c * 2048 + w * 512]);
    }
#pragma unroll
    for (int c = 0; c < RN; ++c) {
      int u = c * 256 + t;
      gload16(Bt + (size_t)(n0 + (u >> 2)) * Kdim + kt * 32 + (u & 3) * 8,
              &lB[buf][c * 2048 + w * 512]);
    }
  };

  // prologue: tile 0
  stage(0, 0);
  asm volatile("s_waitcnt vmcnt(0)" ::: "memory");
  __builtin_amdgcn_s_barrier();
  __builtin_amdgcn_sched_barrier(0);

  for (int kt = 0; kt < nkt; ++kt) {
    const int cur = kt & 1;
    // issue next tile's stage first (overlaps with compute below)
    if (kt + 1 < nkt) stage(cur ^ 1, kt + 1);
    __builtin_amdgcn_sched_barrier(0);

    bf16x8 af[MI], bfr[NJ];
#pragma unroll
    for (int i = 0; i < MI; ++i)
      af[i] = *(const bf16x8*)&lA[cur][(wr + i * 16 + llo) * 32 + lhi * 8];
#pragma unroll
    for (int j = 0; j < NJ; ++j)
      bfr[j] = *(const bf16x8*)&lB[cur][(wc + j * 16 + llo) * 32 + lhi * 8];
#pragma unroll
    for (int i = 0; i < MI; ++i)
#pragma unroll
      for (int j = 0; j < NJ; ++j)
        acc[i][j] = __builtin_amdgcn_mfma_f32_16x16x32_bf16(af[i], bfr[j], acc[i][j], 0, 0, 0);

    // single sync point: prefetch landed (hidden under MFMA) + all waves done
    // reading buf[cur] (every ds_read was MFMA-consumed above -> lgkm drained)
    __builtin_amdgcn_sched_barrier(0);
    asm volatile("s_waitcnt vmcnt(0)" ::: "memory");
    __builtin_amdgcn_s_barrier();
    __builtin_amdgcn_sched_barrier(0);
  }

#pragma unroll
  for (int i = 0; i < MI; ++i) {
    int row = m0 + wr + i * 16 + lhi * 4;
#pragma unroll
    for (int j = 0; j < NJ; ++j) {
      int col = n0 + wc + j * 16 + llo;
#pragma unroll
      for (int r = 0; r < 4; ++r) {
        float v = acc[i][j][r];
        int rr = row + r;
        if (MODE == 0) {
          int qkv = col >> 9, g = (col >> 6) & 7, d = col & 63;
          bf16 bv = (bf16)v;
          if (qkv == 0)
            Qo[((size_t)g * 8192 + rr) * 64 + d] = bv;
          else if (qkv == 1)
            Ko[((size_t)g * 8192 + rr) * 64 + d] = bv;
          else {
            int b = rr >> 9, n = rr & 511;
            Vto[(((size_t)g * 16 + b) * 64 + d) * 512 + n] = bv;
          }
        } else {
          Cf[(size_t)rr * Ndim + col] = v;
        }
      }
    }
  }
}

// ---------- fused attention (round-4 passing version, verbatim) ----------
// grid (8 qtiles, 16 batch, 8 heads), 256 threads (4 waves x 16 q-rows)
// KVBLK=64. Double-buffered LDS KV staged via global_load_lds with
// PRE-SWIZZLED global source (linear LDS dest). Edge bias in a 2-entry
// PARITY-INDEXED register buffer (fully unrolled loop -> static indices).
// Counted vmcnt(8) keeps tile t+1's 8 loads in flight across the compute
// phase. S^T trick: mfma(K,Q) -> lane owns q=llo; P assembled in-register
// via cvt_pk + permlane swaps (T12).
__global__ __launch_bounds__(256, 4) void attn_kernel(
    const bf16* __restrict__ Qa, const bf16* __restrict__ Ka,
    const bf16* __restrict__ Vta, const float* __restrict__ edge,
    bf16* __restrict__ Oatt) {
  __shared__ bf16 lK[2][64 * 64];
  __shared__ bf16 lV[2][64 * 64];
  const int t = threadIdx.x, w = t >> 6, lane = t & 63;
  const int lhi = lane >> 4, llo = lane & 15;
  const int qt = blockIdx.x, b = blockIdx.y, g = blockIdx.z;
  const int q0 = qt * 64 + w * 16;
  const bf16* Qg = Qa + ((size_t)g * 8192 + b * 512) * 64;
  const bf16* Kg = Ka + ((size_t)g * 8192 + b * 512) * 64;
  const bf16* Vg = Vta + ((size_t)g * 16 + b) * (64 * 512);
  const float* eg = edge + ((size_t)g * 16 + b) * (512 * 512);

  // Q fragments (B-operand layout: lane col = llo = q-row)
  bf16x8 qf[2];
#pragma unroll
  for (int ks = 0; ks < 2; ++ks)
    qf[ks] = *(const bf16x8*)(Qg + (size_t)(q0 + llo) * 64 + ks * 32 + lhi * 8);

  f32x4 oacc[4] = {};
  float mrow = -3e38f, lrow = 0.f;

  // staging coords: row = (j*256+t)>>3; pre-swizzled SOURCE col-chunk
  const int r0 = t >> 3;          // rows 0..31 (issue 0)
  const int r1 = r0 + 32;         // rows 32..63 (issue 1), (r1&7)==(r0&7)
  const int cs = (((t & 7) ^ (r0 & 7)) << 3);

  // edge bias double buffer, parity-indexed (static after full unroll)
  f32x4 eb[2][4];

  // ---- prologue: tile 0 (8 vmem ops: 4 gload_lds + 4 edge) ----
  gload16(Kg + (size_t)r0 * 64 + cs, &lK[0][w * 512]);
  gload16(Kg + (size_t)r1 * 64 + cs, &lK[0][2048 + w * 512]);
  gload16(Vg + (size_t)r0 * 512 + cs, &lV[0][w * 512]);
  gload16(Vg + (size_t)r1 * 512 + cs, &lV[0][2048 + w * 512]);
#pragma unroll
  for (int ni = 0; ni < 4; ++ni)
    eb[0][ni] = *(const f32x4*)(eg + (size_t)(q0 + llo) * 512 + ni * 16 + lhi * 4);
  __builtin_amdgcn_sched_barrier(0);

#pragma unroll
  for (int it = 0; it < 8; ++it) {
    const int cur = it & 1, nxt = cur ^ 1;
    const int kv0 = it * 64;

    // ---- issue tile t+1 loads (stay in flight through both barriers) ----
    if (it < 7) {
      const int kvn = kv0 + 64;
      gload16(Kg + (size_t)(kvn + r0) * 64 + cs, &lK[nxt][w * 512]);
      gload16(Kg + (size_t)(kvn + r1) * 64 + cs, &lK[nxt][2048 + w * 512]);
      gload16(Vg + (size_t)r0 * 512 + kvn + cs, &lV[nxt][w * 512]);
      gload16(Vg + (size_t)r1 * 512 + kvn + cs, &lV[nxt][2048 + w * 512]);
#pragma unroll
      for (int ni = 0; ni < 4; ++ni)
        eb[nxt][ni] = *(const f32x4*)(eg + (size_t)(q0 + llo) * 512 + kvn + ni * 16 + lhi * 4);
    }
    // pin the 8 issues above the counted wait, then wait for tile t only
    __builtin_amdgcn_sched_barrier(0);
    if (it < 7)
      asm volatile("s_waitcnt vmcnt(8)" ::: "memory");
    else
      asm volatile("s_waitcnt vmcnt(0)" ::: "memory");
    __builtin_amdgcn_sched_barrier(0);
    __builtin_amdgcn_s_barrier();
    __builtin_amdgcn_sched_barrier(0);

    // ---- S^T = K Q^T : sc[ni][r] = S[q=llo][kv = ni*16 + lhi*4 + r] ----
    f32x4 sc[4] = {};
    __builtin_amdgcn_s_setprio(1);
#pragma unroll
    for (int ks = 0; ks < 2; ++ks) {
      bf16x8 kf[4];
#pragma unroll
      for (int ni = 0; ni < 4; ++ni) {
        int row = ni * 16 + llo;
        kf[ni] = *(const bf16x8*)&lK[cur][(row * 64 + ks * 32 + lhi * 8) ^ ((row & 7) << 3)];
      }
#pragma unroll
      for (int ni = 0; ni < 4; ++ni)
        sc[ni] = __builtin_amdgcn_mfma_f32_16x16x32_bf16(kf[ni], qf[ks], sc[ni], 0, 0, 0);
    }
    __builtin_amdgcn_s_setprio(0);

    // ---- edge add + online softmax (reduce over lhi: 2 shfls) ----
    float mx = -3e38f;
#pragma unroll
    for (int ni = 0; ni < 4; ++ni)
#pragma unroll
      for (int r = 0; r < 4; ++r) {
        float sv = fmaf(ALPHA_, sc[ni][r], eb[cur][ni][r]);
        sc[ni][r] = sv;
        mx = fmaxf(mx, sv);
      }
    mx = fmaxf(mx, __shfl_xor(mx, 16));
    mx = fmaxf(mx, __shfl_xor(mx, 32));
    float mnew = fmaxf(mrow, mx);
    float s = __expf(mrow - mnew);
    mrow = mnew;
    float rsum = 0.f;
#pragma unroll
    for (int ni = 0; ni < 4; ++ni)
#pragma unroll
      for (int r = 0; r < 4; ++r) {
        float p = __expf(sc[ni][r] - mnew);
        sc[ni][r] = p;
        rsum += p;
      }
    rsum += __shfl_xor(rsum, 16);
    rsum += __shfl_xor(rsum, 32);
    lrow = lrow * s + rsum;

    // rescale O accumulator (row r needs scale of q-row lhi*4+r, held at llo=lhi*4+r)
#pragma unroll
    for (int r = 0; r < 4; ++r) {
      float sq = __shfl(s, (lane & 48) | (lhi * 4 + r));
#pragma unroll
      for (int nc = 0; nc < 4; ++nc) oacc[nc][r] *= sq;
    }

    // ---- P A-frag via cvt_pk + permlane swaps; O += P V ----
    __builtin_amdgcn_s_setprio(1);
#pragma unroll
    for (int ks2 = 0; ks2 < 2; ++ks2) {
      const int n0 = ks2 * 2, n1 = n0 + 1;
      unsigned xa, xb, ya, yb;
      asm("v_cvt_pk_bf16_f32 %0, %1, %2" : "=v"(xa) : "v"(sc[n0][0]), "v"(sc[n0][1]));
      asm("v_cvt_pk_bf16_f32 %0, %1, %2" : "=v"(xb) : "v"(sc[n0][2]), "v"(sc[n0][3]));
      asm("v_cvt_pk_bf16_f32 %0, %1, %2" : "=v"(ya) : "v"(sc[n1][0]), "v"(sc[n1][1]));
      asm("v_cvt_pk_bf16_f32 %0, %1, %2" : "=v"(yb) : "v"(sc[n1][2]), "v"(sc[n1][3]));
      asm("v_permlane32_swap_b32 %0, %1" : "+v"(xa), "+v"(ya));
      asm("v_permlane16_swap_b32 %0, %1" : "+v"(xa), "+v"(ya));
      asm("v_permlane32_swap_b32 %0, %1" : "+v"(xb), "+v"(yb));
      asm("v_permlane16_swap_b32 %0, %1" : "+v"(xb), "+v"(yb));
      union { unsigned wd[4]; bf16x8 v; } fu;
      fu.wd[0] = xa; fu.wd[1] = xb; fu.wd[2] = ya; fu.wd[3] = yb;
      bf16x8 pf = fu.v;

      bf16x8 vf[4];
#pragma unroll
      for (int nc = 0; nc < 4; ++nc) {
        int row = nc * 16 + llo;
        vf[nc] = *(const bf16x8*)&lV[cur][(row * 64 + ks2 * 32 + lhi * 8) ^ ((row & 7) << 3)];
      }
#pragma unroll
      for (int nc = 0; nc < 4; ++nc)
        oacc[nc] = __builtin_amdgcn_mfma_f32_16x16x32_bf16(pf, vf[nc], oacc[nc], 0, 0, 0);
    }
    __builtin_amdgcn_s_setprio(0);

    if (it < 7) {
      // barrier B: all waves done reading buf[cur] before next iter's
      // gload_lds overwrites it
      __builtin_amdgcn_sched_barrier(0);
      __builtin_amdgcn_s_barrier();
      __builtin_amdgcn_sched_barrier(0);
    }
  }

  // ---- normalize + write Oatt [b*512+q][g*64+d] ----
  float rcpl = 1.0f / lrow;
#pragma unroll
  for (int r = 0; r < 4; ++r) {
    float lr = __shfl(rcpl, (lane & 48) | (lhi * 4 + r));
    int qrow = q0 + lhi * 4 + r;
#pragma unroll
    for (int nc = 0; nc < 4; ++nc) {
      float ov = oacc[nc][r] * lr;
      Oatt[((size_t)b * 512 + qrow) * 512 + g * 64 + nc * 16 + llo] = (bf16)ov;
    }
  }
}

// ---------- launch ----------
extern "C" void kernel_launch(void* const* d_in, const int* in_sizes, int n_in,
                              void* d_out, int out_size, void* d_ws, size_t ws_size,
                              hipStream_t stream) {
  (void)in_sizes; (void)n_in; (void)out_size; (void)ws_size;
  const float* x = (const float*)d_in[0];
  const float* edge = (const float*)d_in[1];
  const float* Wq = (const float*)d_in[2];
  const float* Wk = (const float*)d_in[3];
  const float* Wv = (const float*)d_in[4];
  const float* Wo = (const float*)d_in[5];
  float* out = (float*)d_out;

  char* ws = (char*)d_ws;
  bf16* xb   = (bf16*)(ws + 0);
  bf16* wcat = (bf16*)(ws + 8388608);
  bf16* wot  = (bf16*)(ws + 9961472);
  bf16* Qa   = (bf16*)(ws + 10485760);
  bf16* Ka   = (bf16*)(ws + 18874368);
  bf16* Vta  = (bf16*)(ws + 27262976);
  bf16* Oatt = (bf16*)(ws + 35651584);

  cast_x_kernel<<<4096, 256, 0, stream>>>(x, xb);
  prep_w_kernel<<<3072, 256, 0, stream>>>(Wq, Wk, Wv, wcat);
  prep_wo_kernel<<<1024, 256, 0, stream>>>(Wo, wot);

  // QKV: A=xb [8192,512], Bt=wcat [1536,512], tile 128x128
  gemm2_kernel<2, 2, 0><<<dim3(12, 64), 256, 0, stream>>>(xb, wcat, 512, 1536,
                                                          nullptr, Qa, Ka, Vta);
  // fused attention
  attn_kernel<<<dim3(8, 16, 8), 256, 0, stream>>>(Qa, Ka, Vta, edge, Oatt);
  // output projection: A=Oatt [8192,512], Bt=wot [512,512], tile 128x64 -> f32
  gemm2_kernel<2, 1, 1><<<dim3(8, 64), 256, 0, stream>>>(Oatt, wot, 512, 512,
                                                         out, nullptr, nullptr, nullptr);
}